// Round 1
// baseline (1444.925 us; speedup 1.0000x reference)
//
#include <hip/hip_runtime.h>
#include <hip/hip_bf16.h>
#include <stdint.h>
#include <stddef.h>

#define N_NODES 10000
#define N_EDGES 320000
#define KPAD    10240     // padded j-dimension (bits per reach2 row, NT_T cols)
#define MPAD    10112     // padded node rows for feat2 (79 * 128)
#define WORDS   320       // KPAD / 32

typedef __hip_bfloat16 bf16;
typedef short  short8 __attribute__((ext_vector_type(8)));   // 8 bf16 (4 VGPRs)
typedef float  f32x4  __attribute__((ext_vector_type(4)));   // MFMA accumulator

// ------------------------------------------------------------------
// x -> bf16 ; We -> We^T bf16  [256][512]
__global__ void convert_kernel(const float* __restrict__ x, bf16* __restrict__ xb,
                               const float* __restrict__ We, bf16* __restrict__ WeT) {
  int i = blockIdx.x * 256 + threadIdx.x;
  if (i < N_NODES * 256) xb[i] = __float2bfloat16(x[i]);
  if (i < 512 * 256) {
    int h = i >> 9, k = i & 511;
    WeT[i] = __float2bfloat16(We[k * 256 + h]);
  }
}

// ------------------------------------------------------------------
// per-edge: degree count + adjacency bitmap
__global__ void count_kernel(const int* __restrict__ ei, int* __restrict__ cnt,
                             unsigned* __restrict__ A) {
  int e = blockIdx.x * 256 + threadIdx.x;
  if (e >= N_EDGES) return;
  int r = ei[e], c = ei[N_EDGES + e];
  atomicAdd(&cnt[r], 1);
  atomicOr(&A[(size_t)r * WORDS + (c >> 5)], 1u << (c & 31));
}

// single-block exclusive scan -> row_ptr
__global__ __launch_bounds__(1024) void scan_kernel(const int* __restrict__ cnt,
                                                    int* __restrict__ row_ptr) {
  __shared__ int ps[1024];
  int t = threadIdx.x;
  const int C = 10;   // 1024*10 >= 10000
  int base = t * C;
  int local[C];
  int s = 0;
#pragma unroll
  for (int c = 0; c < C; ++c) {
    int idx = base + c;
    int v = (idx < N_NODES) ? cnt[idx] : 0;
    local[c] = s; s += v;
  }
  ps[t] = s;
  __syncthreads();
  for (int off = 1; off < 1024; off <<= 1) {
    int v = (t >= off) ? ps[t - off] : 0;
    __syncthreads();
    ps[t] += v;
    __syncthreads();
  }
  int pre = (t > 0) ? ps[t - 1] : 0;
#pragma unroll
  for (int c = 0; c < C; ++c) {
    int idx = base + c;
    if (idx < N_NODES) row_ptr[idx] = pre + local[c];
  }
  __syncthreads();
  if (t == 0) row_ptr[N_NODES] = ps[1023];
}

__global__ void scatter_kernel(const int* __restrict__ ei, const int* __restrict__ row_ptr,
                               int* __restrict__ cursor, int* __restrict__ col_idx) {
  int e = blockIdx.x * 256 + threadIdx.x;
  if (e >= N_EDGES) return;
  int r = ei[e], c = ei[N_EDGES + e];
  int p = atomicAdd(&cursor[r], 1);
  col_idx[row_ptr[r] + p] = c;
}

// ------------------------------------------------------------------
// reach2 row = OR of A rows of neighbors; clear self bit; inv_cnt2
__global__ __launch_bounds__(320) void reach2_kernel(const int* __restrict__ row_ptr,
                                                     const int* __restrict__ col_idx,
                                                     const unsigned* __restrict__ A,
                                                     unsigned* __restrict__ reach2,
                                                     float* __restrict__ inv_cnt2) {
  __shared__ int cnt;
  int i = blockIdx.x;
  int t = threadIdx.x;           // 0..319 (one word each)
  if (t == 0) cnt = 0;
  __syncthreads();
  int s = row_ptr[i], e = row_ptr[i + 1];
  unsigned acc = 0;
  for (int p = s; p < e; ++p) {
    int j = col_idx[p];
    acc |= A[(size_t)j * WORDS + t];
  }
  if (t == (i >> 5)) acc &= ~(1u << (i & 31));
  reach2[(size_t)i * WORDS + t] = acc;
  atomicAdd(&cnt, __popc(acc));
  __syncthreads();
  if (t == 0) inv_cnt2[i] = (cnt > 0) ? 1.0f / (float)cnt : 0.0f;
}

// ------------------------------------------------------------------
// 1-hop mean (duplicates counted, per reference) — f32 gather
__global__ __launch_bounds__(256) void nbr_kernel(const int* __restrict__ row_ptr,
                                                  const int* __restrict__ col_idx,
                                                  const float* __restrict__ NT,
                                                  float* __restrict__ nbr_mean) {
  int i = blockIdx.x;
  int t = threadIdx.x;
  int s = row_ptr[i], e = row_ptr[i + 1];
  float acc = 0.0f;
  for (int p = s; p < e; ++p) {
    int j = col_idx[p];
    acc += NT[(size_t)j * 256 + t];
  }
  float d = (float)(e - s);
  nbr_mean[(size_t)i * 256 + t] = (d > 0.0f) ? acc / d : 0.0f;
}

// ------------------------------------------------------------------
// node_tokens f32 [10000][256] -> NT^T bf16 [256][KPAD]
__global__ __launch_bounds__(256) void transpose_nt(const float* __restrict__ NT,
                                                    bf16* __restrict__ NTT) {
  __shared__ float tile[32][33];
  int jb = (blockIdx.x % 313) * 32;       // node rows
  int cb = (blockIdx.x / 313) * 32;       // feature cols
  int t = threadIdx.x;
  int tr = t >> 5, tc = t & 31;
#pragma unroll
  for (int i = 0; i < 4; ++i) {
    int j = jb + tr + i * 8;
    tile[tr + i * 8][tc] = (j < N_NODES) ? NT[(size_t)j * 256 + cb + tc] : 0.0f;
  }
  __syncthreads();
#pragma unroll
  for (int i = 0; i < 4; ++i) {
    int h = cb + tr + i * 8;
    int j = jb + tc;
    if (j < N_NODES) NTT[(size_t)h * KPAD + j] = __float2bfloat16(tile[tc][tr + i * 8]);
  }
}

// ------------------------------------------------------------------
// generic fp32 linear: out = act([in0|in1|in2*scale2] @ W + b), M=10000 rows
template <int NIN, bool RELU>
__global__ __launch_bounds__(256) void linear_kernel(
    const float* __restrict__ in0, const float* __restrict__ in1,
    const float* __restrict__ in2, const float* __restrict__ scale2,
    const float* __restrict__ W, const float* __restrict__ bias,
    float* __restrict__ out) {
  __shared__ float Xs[32][64];
  int t = threadIdx.x;
  int rowbase = blockIdx.x * 32;
  int rgrp = t >> 6;       // wave id: rows rgrp*8 .. +8
  int c0 = t & 63;         // cols c0, c0+64, c0+128, c0+192
  float acc[8][4];
#pragma unroll
  for (int r = 0; r < 8; ++r)
#pragma unroll
    for (int j = 0; j < 4; ++j) acc[r][j] = 0.0f;

  const int NCH = NIN * 4;
  for (int ch = 0; ch < NCH; ++ch) {
    const float* src = (ch >> 2) == 0 ? in0 : ((ch >> 2) == 1 ? in1 : in2);
    int koff = (ch & 3) * 64;
    __syncthreads();
#pragma unroll
    for (int i = 0; i < 8; ++i) {
      int idx = i * 256 + t;
      int r = idx >> 6, kk = idx & 63;
      int grow = rowbase + r;
      float v = 0.0f;
      if (grow < N_NODES) {
        v = src[(size_t)grow * 256 + koff + kk];
        if (NIN == 3 && (ch >> 2) == 2) v *= scale2[grow];
      }
      Xs[r][kk] = v;
    }
    __syncthreads();
    int kglob = ch * 64;
#pragma unroll 4
    for (int kk = 0; kk < 64; ++kk) {
      const float* wrow = W + (size_t)(kglob + kk) * 256 + c0;
      float w0 = wrow[0], w1 = wrow[64], w2 = wrow[128], w3 = wrow[192];
      float xv[8];
#pragma unroll
      for (int r = 0; r < 8; ++r) xv[r] = Xs[rgrp * 8 + r][kk];
#pragma unroll
      for (int r = 0; r < 8; ++r) {
        acc[r][0] += xv[r] * w0;
        acc[r][1] += xv[r] * w1;
        acc[r][2] += xv[r] * w2;
        acc[r][3] += xv[r] * w3;
      }
    }
  }
#pragma unroll
  for (int j = 0; j < 4; ++j) {
    int c = c0 + j * 64;
    float b = bias[c];
#pragma unroll
    for (int r = 0; r < 8; ++r) {
      int grow = rowbase + rgrp * 8 + r;
      if (grow < N_NODES) {
        float v = acc[r][j] + b;
        if (RELU) v = fmaxf(v, 0.0f);
        out[(size_t)grow * 256 + c] = v;
      }
    }
  }
}

// ------------------------------------------------------------------
// edge GEMM: edge_tokens[e][h] = [x[row]|x[col]] @ We + be   (bf16 MFMA)
// block: 512 thr = 8 waves, M-tile 128 edges, N=256, K=512 (step 32)
__global__ __launch_bounds__(512) void edge_gemm(const bf16* __restrict__ xb,
                                                 const int* __restrict__ ei,
                                                 const bf16* __restrict__ WeT,
                                                 const float* __restrict__ be,
                                                 float* __restrict__ out) {
  __shared__ short BsT[256][40];   // B^T slice [n=256][k=32] padded to 40
  int tid = threadIdx.x;
  int wave = tid >> 6, lane = tid & 63;
  int l16 = lane & 15, g = lane >> 4;
  int ebase = blockIdx.x * 128 + wave * 16;
  int er = ei[ebase + l16];
  int ec = ei[N_EDGES + ebase + l16];
  f32x4 acc[16];
#pragma unroll
  for (int nt = 0; nt < 16; ++nt) acc[nt] = (f32x4){0.f, 0.f, 0.f, 0.f};

  int sh = tid >> 1, shalf = tid & 1;   // staging: 2 threads per B^T row
  for (int ks = 0; ks < 16; ++ks) {
    int kbase = ks * 32;
    // issue global loads early (staging + A-fragment)
    const uint4* s = (const uint4*)(const void*)(WeT + (size_t)sh * 512 + kbase + shalf * 16);
    uint4 v0 = s[0], v1 = s[1];
    int koff = kbase + g * 8;
    int node = (koff < 256) ? er : ec;
    short8 fa = *(const short8*)(const void*)(xb + (size_t)node * 256 + (koff & 255));
    __syncthreads();                      // previous iter done reading BsT
    uint4* d = (uint4*)(void*)&BsT[sh][shalf * 16];
    d[0] = v0; d[1] = v1;
    __syncthreads();
#pragma unroll
    for (int nt = 0; nt < 16; ++nt) {
      short8 fb = *(const short8*)(const void*)&BsT[nt * 16 + l16][g * 8];
      acc[nt] = __builtin_amdgcn_mfma_f32_16x16x32_bf16(fa, fb, acc[nt], 0, 0, 0);
    }
  }
  int erow = ebase + g * 4;
#pragma unroll
  for (int nt = 0; nt < 16; ++nt) {
    int c = nt * 16 + l16;
    float b = be[c];
#pragma unroll
    for (int r = 0; r < 4; ++r)
      out[(size_t)(erow + r) * 256 + c] = acc[nt][r] + b;
  }
}

// ------------------------------------------------------------------
// feat2 GEMM: fws[i][h] += sum_j reach2bit(i,j) * NT[j][h]  (bf16 MFMA, K-split 8)
#define KSPLIT 8
__global__ __launch_bounds__(512) void feat2_gemm(const unsigned* __restrict__ reach2,
                                                  const bf16* __restrict__ NTT,
                                                  float* __restrict__ fws) {
  __shared__ short BsT[256][40];
  int tid = threadIdx.x;
  int wave = tid >> 6, lane = tid & 63;
  int l16 = lane & 15, g = lane >> 4;
  int mt = blockIdx.x / KSPLIT;
  int kc = blockIdx.x % KSPLIT;
  int ibase = mt * 128 + wave * 16;
  const uint8_t* abytes = (const uint8_t*)reach2 + (size_t)(ibase + l16) * (WORDS * 4);
  f32x4 acc[16];
#pragma unroll
  for (int nt = 0; nt < 16; ++nt) acc[nt] = (f32x4){0.f, 0.f, 0.f, 0.f};

  int sh = tid >> 1, shalf = tid & 1;
  const int KSTEPS = (KPAD / 32) / KSPLIT;   // 40
  for (int ks = kc * KSTEPS; ks < kc * KSTEPS + KSTEPS; ++ks) {
    int kbase = ks * 32;
    const uint4* s = (const uint4*)(const void*)(NTT + (size_t)sh * KPAD + kbase + shalf * 16);
    uint4 v0 = s[0], v1 = s[1];
    unsigned bits = abytes[(kbase >> 3) + g];
    __syncthreads();
    uint4* d = (uint4*)(void*)&BsT[sh][shalf * 16];
    d[0] = v0; d[1] = v1;
    __syncthreads();
    short8 fa;
#pragma unroll
    for (int b = 0; b < 8; ++b) fa[b] = ((bits >> b) & 1) ? (short)0x3F80 : (short)0;
#pragma unroll
    for (int nt = 0; nt < 16; ++nt) {
      short8 fb = *(const short8*)(const void*)&BsT[nt * 16 + l16][g * 8];
      acc[nt] = __builtin_amdgcn_mfma_f32_16x16x32_bf16(fa, fb, acc[nt], 0, 0, 0);
    }
  }
  int irow = ibase + g * 4;
#pragma unroll
  for (int nt = 0; nt < 16; ++nt) {
    int c = nt * 16 + l16;
#pragma unroll
    for (int r = 0; r < 4; ++r)
      atomicAdd(&fws[(size_t)(irow + r) * 256 + c], acc[nt][r]);
  }
}

// ------------------------------------------------------------------
extern "C" void kernel_launch(void* const* d_in, const int* in_sizes, int n_in,
                              void* d_out, int out_size, void* d_ws, size_t ws_size,
                              hipStream_t stream) {
  const float* x   = (const float*)d_in[0];
  const int*   ei  = (const int*)d_in[1];
  const float* Wn  = (const float*)d_in[2];
  const float* bn  = (const float*)d_in[3];
  const float* We  = (const float*)d_in[4];
  const float* be  = (const float*)d_in[5];
  const float* Ws1 = (const float*)d_in[6];
  const float* bs1 = (const float*)d_in[7];
  const float* Ws2 = (const float*)d_in[8];
  const float* bs2 = (const float*)d_in[9];
  const float* Wh1 = (const float*)d_in[10];
  const float* bh1 = (const float*)d_in[11];
  const float* Wh2 = (const float*)d_in[12];
  const float* bh2 = (const float*)d_in[13];

  float* out          = (float*)d_out;
  float* node_tokens  = out;                       // [10000][256]
  float* edge_tokens  = out + 2560000;             // [320000][256]
  float* subgraph     = out + 84480000;            // [10000][256]
  float* nbhd         = out + 87040000;            // [10000][256]

  char* p = (char*)d_ws;
  auto alloc = [&](size_t bytes) -> void* {
    void* r = (void*)p;
    p += (bytes + 511) & ~(size_t)511;
    return r;
  };
  bf16*     xb       = (bf16*)alloc((size_t)N_NODES * 256 * 2);        // 5.12 MB
  bf16*     WeT      = (bf16*)alloc((size_t)256 * 512 * 2);            // 256 KB
  bf16*     NTT      = (bf16*)alloc((size_t)256 * KPAD * 2);           // 5.24 MB
  int*      cnt      = (int*)alloc((size_t)N_NODES * 4);
  int*      row_ptr  = (int*)alloc((size_t)(N_NODES + 1) * 4);
  int*      cursor   = (int*)alloc((size_t)N_NODES * 4);
  int*      col_idx  = (int*)alloc((size_t)N_EDGES * 4);               // 1.28 MB
  unsigned* A        = (unsigned*)alloc((size_t)N_NODES * WORDS * 4);  // 12.8 MB
  unsigned* reach2   = (unsigned*)alloc((size_t)MPAD * WORDS * 4);     // 12.9 MB
  float*    inv_cnt2 = (float*)alloc((size_t)MPAD * 4);
  float*    nbr_mean = (float*)alloc((size_t)N_NODES * 256 * 4);       // 10.24 MB
  float*    fws      = (float*)alloc((size_t)MPAD * 256 * 4);          // 10.35 MB
  float*    h1       = (float*)alloc((size_t)N_NODES * 256 * 4);       // 10.24 MB

  hipMemsetAsync(cnt, 0, (size_t)N_NODES * 4, stream);
  hipMemsetAsync(cursor, 0, (size_t)N_NODES * 4, stream);
  hipMemsetAsync(A, 0, (size_t)N_NODES * WORDS * 4, stream);
  hipMemsetAsync(reach2, 0, (size_t)MPAD * WORDS * 4, stream);
  hipMemsetAsync(NTT, 0, (size_t)256 * KPAD * 2, stream);
  hipMemsetAsync(fws, 0, (size_t)MPAD * 256 * 4, stream);

  convert_kernel<<<10000, 256, 0, stream>>>(x, xb, We, WeT);
  count_kernel<<<1250, 256, 0, stream>>>(ei, cnt, A);
  scan_kernel<<<1, 1024, 0, stream>>>(cnt, row_ptr);
  scatter_kernel<<<1250, 256, 0, stream>>>(ei, row_ptr, cursor, col_idx);

  // node tokens (f32) then its bf16 transpose
  linear_kernel<1, false><<<313, 256, 0, stream>>>(x, nullptr, nullptr, nullptr,
                                                   Wn, bn, node_tokens);
  transpose_nt<<<313 * 8, 256, 0, stream>>>(node_tokens, NTT);

  reach2_kernel<<<N_NODES, 320, 0, stream>>>(row_ptr, col_idx, A, reach2, inv_cnt2);
  nbr_kernel<<<N_NODES, 256, 0, stream>>>(row_ptr, col_idx, node_tokens, nbr_mean);

  edge_gemm<<<N_EDGES / 128, 512, 0, stream>>>(xb, ei, WeT, be, edge_tokens);
  feat2_gemm<<<(MPAD / 128) * KSPLIT, 512, 0, stream>>>(reach2, NTT, fws);

  // subgraph MLP
  linear_kernel<2, true><<<313, 256, 0, stream>>>(node_tokens, nbr_mean, nullptr, nullptr,
                                                  Ws1, bs1, h1);
  linear_kernel<1, false><<<313, 256, 0, stream>>>(h1, nullptr, nullptr, nullptr,
                                                   Ws2, bs2, subgraph);
  // neighborhood MLP (feat2 = fws * inv_cnt2 applied on load)
  linear_kernel<3, true><<<313, 256, 0, stream>>>(node_tokens, nbr_mean, fws, inv_cnt2,
                                                  Wh1, bh1, h1);
  linear_kernel<1, false><<<313, 256, 0, stream>>>(h1, nullptr, nullptr, nullptr,
                                                   Wh2, bh2, nbhd);
}